// Round 7
// baseline (534.046 us; speedup 1.0000x reference)
//
#include <hip/hip_runtime.h>
#include <stdint.h>

typedef unsigned short u16;
typedef unsigned int u32;
typedef __attribute__((ext_vector_type(8))) short bf16x8;
typedef __attribute__((ext_vector_type(4))) short s16x4;
typedef __attribute__((ext_vector_type(4))) float f32x4;
typedef __attribute__((ext_vector_type(2))) float f32x2;

#define DEV __device__ __forceinline__

DEV u16 f2bf(float f) {
  union { float f; unsigned u; } v; v.f = f;
  unsigned r = v.u + 0x7fffu + ((v.u >> 16) & 1u);
  return (u16)(r >> 16);
}
DEV float bf2f(u16 h) {
  union { u32 u; float f; } v; v.u = ((u32)h) << 16; return v.f;
}
DEV float lo16(u32 w) { union { u32 u; float f; } v; v.u = w << 16; return v.f; }
DEV float hi16(u32 w) { union { u32 u; float f; } v; v.u = w & 0xFFFF0000u; return v.f; }
DEV int imax(int a, int b) { return a > b ? a : b; }
DEV int imin(int a, int b) { return a < b ? a : b; }

// bijective XCD-chunk swizzle (m204 form) — used ONLY within GEMM segments,
// where neighbor tiles share operand panels. NEVER applied across a
// heterogeneous grid (would pin one segment onto a single XCD).
DEV int xcd_swz(int b0, int nwg) {
  int q = nwg >> 3, r = nwg & 7, x = b0 & 7, l = b0 >> 3;
  return (x < r ? x * (q + 1) : r * (q + 1) + (x - r) * q) + l;
}

DEV void g2lds16(const u16* g, u16* l) {
  __builtin_amdgcn_global_load_lds(
      (const __attribute__((address_space(1))) void*)g,
      (__attribute__((address_space(3))) void*)l, 16, 0, 0);
}

// att_comb writer: one block streams row i (video + audio halves) with NT
// stores from the L2-hot band buffers. bw = 80-float shared scratch.
DEV void write_att_row(int i, const float* __restrict__ bandV,
                       const float* __restrict__ bandA,
                       float* __restrict__ attBase, int N, int tid,
                       float* bw) {
  const int lo = imax(i - 19, 0);
  const int hi = imin(i + 19, N - 1);
  if (tid < 40) bw[tid] = bandV[i * 40 + tid];
  else if (tid < 80) bw[tid] = bandA[i * 40 + (tid - 40)];
  __syncthreads();
  const int nch = N / 4;
  const int cLo = lo >> 2, cHi = hi >> 2;
  f32x4* rowp = (f32x4*)(attBase + (size_t)i * 2 * N);
#pragma unroll 1
  for (int half = 0; half < 2; ++half) {
    const float* w = bw + half * 40;
    f32x4* rp = rowp + half * nch;
    for (int c = tid; c < nch; c += 256) {
      f32x4 o = {0.f, 0.f, 0.f, 0.f};
      if (c >= cLo && c <= cHi) {
        int col0 = c * 4;
#pragma unroll
        for (int e2 = 0; e2 < 4; ++e2) {
          int col = col0 + e2;
          if (col >= lo && col <= hi) o[e2] = w[col - lo];
        }
      }
      __builtin_nontemporal_store(o, &rp[c]);
    }
  }
}

// ---------------------------------------------------------------------------
// merged prep: multi-segment f32->bf16 cast  +  32x32 tiled transpose->bf16
// ---------------------------------------------------------------------------
#define NSEG 5
struct CastTab {
  const float* src[NSEG];
  u16* dst[NSEG];
  int start[NSEG + 1];
};
struct TransTab {
  const float* src[6];
  u16* dst[6];
  int n[6];
  int start[7];
};

__global__ __launch_bounds__(256) void vas_prep(CastTab t, int total4,
                                                int castBlocks, TransTab tt) {
  if ((int)blockIdx.x < castBlocks) {
    int idx = blockIdx.x * 256 + threadIdx.x;
    if (idx >= total4) return;
    int s = 0;
#pragma unroll
    for (int k = 1; k < NSEG; ++k)
      if (idx >= t.start[k]) s = k;
    int local = idx - t.start[s];
    f32x4 f = ((const f32x4*)t.src[s])[local];
    s16x4 o;
    o.x = (short)f2bf(f.x);
    o.y = (short)f2bf(f.y);
    o.z = (short)f2bf(f.z);
    o.w = (short)f2bf(f.w);
    ((s16x4*)t.dst[s])[local] = o;
  } else {
    __shared__ float tl[32][33];
    int b = blockIdx.x - castBlocks;
    int s = 0;
#pragma unroll
    for (int k = 1; k < 6; ++k)
      if (b >= tt.start[k]) s = k;
    b -= tt.start[s];
    const float* src = tt.src[s];
    u16* dst = tt.dst[s];
    const int n = tt.n[s];
    const int tpr = n >> 5;
    const int tr = (b / tpr) * 32, tc = (b % tpr) * 32;
    const int lx = threadIdx.x & 31, ly = threadIdx.x >> 5;
#pragma unroll
    for (int r = 0; r < 4; ++r)
      tl[ly + r * 8][lx] = src[(size_t)(tr + ly + r * 8) * n + tc + lx];
    __syncthreads();
#pragma unroll
    for (int r = 0; r < 4; ++r)
      dst[(size_t)(tc + ly + r * 8) * n + tr + lx] = f2bf(tl[lx][ly + r * 8]);
  }
}

// ---------------------------------------------------------------------------
// 4-way segmented bf16 GEMM, BK=64 (two m97-layout K-half LDS buffers per
// operand; 2 barriers per 64 K). Group-m swizzle for L2 + bijective
// XCD-aware swizzle (m204 form).
// mode 0: f32 out; 1: bf16 relu+bias; 2: bf16 plain. K % 64 == 0.
// ---------------------------------------------------------------------------
struct GemmP {
  const u16* A;
  const u16* W;
  void* C;
  const float* bias;
  int M, Nn, K, mode;
};

__global__ __launch_bounds__(256) void vas_gemm4(
    GemmP p0, GemmP p1, GemmP p2, GemmP p3, int s1, int s2, int s3) {
  const int bs = xcd_swz(blockIdx.x, gridDim.x);

  GemmP p;
  int bid;
  if (bs < s1) { p = p0; bid = bs; }
  else if (bs < s2) { p = p1; bid = bs - s1; }
  else if (bs < s3) { p = p2; bid = bs - s2; }
  else { p = p3; bid = bs - s3; }

  __shared__ u16 As[2][128 * 32];
  __shared__ u16 Ws[2][128 * 32];
  const int tid = threadIdx.x;
  const int lane = tid & 63;
  const int wave = tid >> 6;

  const int Mb = p.M >> 7, Nb = p.Nn >> 7;
  const int GM = 8;
  int per = GM * Nb;
  int g = bid / per;
  int rem = bid - g * per;
  int gm = imin(GM, Mb - g * GM);
  int mblk = g * GM + rem % gm;
  int nblk = rem / gm;
  const int m0 = mblk * 128;
  const int n0 = nblk * 128;
  const int wm = (wave >> 1) * 64;
  const int wn = (wave & 1) * 64;

  // wave-uniform staging decode: waves 0,1 stage A (khalf 0,1), waves 2,3 W.
  const int smat = wave >> 1;          // 0: A, 1: W
  const int skh = wave & 1;            // K-half
  const u16* ssrc = smat ? p.W : p.A;
  const int sbase = smat ? n0 : m0;
  u16* sdstBase = (smat ? &Ws[skh][0] : &As[skh][0]) + lane * 8;
  const int srow = lane >> 2;          // 0..15 within 16-row panel
  const int scol = (lane & 3) * 8;

  f32x4 acc[4][4] = {};

  for (int k0 = 0; k0 < p.K; k0 += 64) {
#pragma unroll
    for (int u = 0; u < 8; ++u) {
      int r0 = u * 16;
      g2lds16(ssrc + (size_t)(sbase + r0 + srow) * p.K + (k0 + skh * 32 + scol),
              sdstBase + r0 * 32);
    }
    __syncthreads();
#pragma unroll
    for (int kk = 0; kk < 2; ++kk) {
      bf16x8 af[4], bfr[4];
#pragma unroll
      for (int t = 0; t < 4; ++t)
        af[t] = *(const bf16x8*)(&As[kk][0] + (wm + t * 16 + (lane & 15)) * 32 + (lane >> 4) * 8);
#pragma unroll
      for (int t = 0; t < 4; ++t)
        bfr[t] = *(const bf16x8*)(&Ws[kk][0] + (wn + t * 16 + (lane & 15)) * 32 + (lane >> 4) * 8);
#pragma unroll
      for (int mi = 0; mi < 4; ++mi)
#pragma unroll
        for (int ni = 0; ni < 4; ++ni)
          acc[mi][ni] = __builtin_amdgcn_mfma_f32_16x16x32_bf16(af[mi], bfr[ni], acc[mi][ni], 0, 0, 0);
    }
    __syncthreads();
  }

#pragma unroll
  for (int mi = 0; mi < 4; ++mi) {
#pragma unroll
    for (int ni = 0; ni < 4; ++ni) {
      int col = n0 + wn + ni * 16 + (lane & 15);
      float bv = p.bias ? p.bias[col] : 0.f;
#pragma unroll
      for (int r = 0; r < 4; ++r) {
        int row = m0 + wm + mi * 16 + (lane >> 4) * 4 + r;
        float vv = acc[mi][ni][r] + bv;
        size_t idx = (size_t)row * p.Nn + col;
        if (p.mode == 0) ((float*)p.C)[idx] = vv;
        else if (p.mode == 1) ((u16*)p.C)[idx] = f2bf(fmaxf(vv, 0.f));
        else ((u16*)p.C)[idx] = f2bf(vv);
      }
    }
  }
}

// ---------------------------------------------------------------------------
// h-GEMM with fused head partials + appended att_comb writer blocks
// (rows [wsplit, N) — the rest ride on vas_apply_ln for earlier overlap).
// Segmentation on RAW blockIdx (GEMM first in dispatch order); xcd_swz only
// within the GEMM segment.
// ---------------------------------------------------------------------------
__global__ __launch_bounds__(256) void vas_gemmh(
    GemmP p, const float* __restrict__ kw, const float* __restrict__ gw,
    float* __restrict__ part, int bh,
    const float* __restrict__ bandV, const float* __restrict__ bandA,
    float* __restrict__ attBase, int N, int wsplit) {
  const int tid = threadIdx.x;

  if ((int)blockIdx.x >= bh) {
    __shared__ float bw[80];
    write_att_row(wsplit + (blockIdx.x - bh), bandV, bandA, attBase, N, tid, bw);
    return;
  }

  const int bid = xcd_swz(blockIdx.x, bh);

  __shared__ u16 As[2][128 * 32];
  __shared__ u16 Ws[2][128 * 32];
  __shared__ float hp[2][128][3];
  const int lane = tid & 63;
  const int wave = tid >> 6;

  const int Mb = p.M >> 7, Nb = p.Nn >> 7;
  const int GM = 8;
  int per = GM * Nb;
  int g = bid / per;
  int rem = bid - g * per;
  int gm = imin(GM, Mb - g * GM);
  int mblk = g * GM + rem % gm;
  int nblk = rem / gm;
  const int m0 = mblk * 128;
  const int n0 = nblk * 128;
  const int wm = (wave >> 1) * 64;
  const int wn = (wave & 1) * 64;

  const int smat = wave >> 1;
  const int skh = wave & 1;
  const u16* ssrc = smat ? p.W : p.A;
  const int sbase = smat ? n0 : m0;
  u16* sdstBase = (smat ? &Ws[skh][0] : &As[skh][0]) + lane * 8;
  const int srow = lane >> 2;
  const int scol = (lane & 3) * 8;

  f32x4 acc[4][4] = {};

  for (int k0 = 0; k0 < p.K; k0 += 64) {
#pragma unroll
    for (int u = 0; u < 8; ++u) {
      int r0 = u * 16;
      g2lds16(ssrc + (size_t)(sbase + r0 + srow) * p.K + (k0 + skh * 32 + scol),
              sdstBase + r0 * 32);
    }
    __syncthreads();
#pragma unroll
    for (int kk = 0; kk < 2; ++kk) {
      bf16x8 af[4], bfr[4];
#pragma unroll
      for (int t = 0; t < 4; ++t)
        af[t] = *(const bf16x8*)(&As[kk][0] + (wm + t * 16 + (lane & 15)) * 32 + (lane >> 4) * 8);
#pragma unroll
      for (int t = 0; t < 4; ++t)
        bfr[t] = *(const bf16x8*)(&Ws[kk][0] + (wn + t * 16 + (lane & 15)) * 32 + (lane >> 4) * 8);
#pragma unroll
      for (int mi = 0; mi < 4; ++mi)
#pragma unroll
        for (int ni = 0; ni < 4; ++ni)
          acc[mi][ni] = __builtin_amdgcn_mfma_f32_16x16x32_bf16(af[mi], bfr[ni], acc[mi][ni], 0, 0, 0);
    }
    __syncthreads();
  }

  // per-row head partials: 16-lane shfl tree over cols, LDS pair-sum of the
  // two waves covering the same 64 rows.
  float kwg[4], bb[4];
#pragma unroll
  for (int ni = 0; ni < 4; ++ni) {
    int col = n0 + wn + ni * 16 + (lane & 15);
    kwg[ni] = kw[col] * gw[col];
    bb[ni] = p.bias ? p.bias[col] : 0.f;
  }
#pragma unroll
  for (int mi = 0; mi < 4; ++mi) {
#pragma unroll
    for (int r = 0; r < 4; ++r) {
      float s1 = 0.f, s2 = 0.f, dd = 0.f;
#pragma unroll
      for (int ni = 0; ni < 4; ++ni) {
        float vv = fmaxf(acc[mi][ni][r] + bb[ni], 0.f);
        s1 += vv;
        s2 += vv * vv;
        dd += vv * kwg[ni];
      }
#pragma unroll
      for (int off = 1; off < 16; off <<= 1) {
        s1 += __shfl_xor(s1, off);
        s2 += __shfl_xor(s2, off);
        dd += __shfl_xor(dd, off);
      }
      if ((lane & 15) == 0) {
        int row = wm + mi * 16 + (lane >> 4) * 4 + r;
        hp[wave & 1][row][0] = s1;
        hp[wave & 1][row][1] = s2;
        hp[wave & 1][row][2] = dd;
      }
    }
  }
  __syncthreads();
  if (tid < 128) {
    float* pp = part + ((size_t)(m0 + tid) * 8 + nblk) * 3;
    pp[0] = hp[0][tid][0] + hp[1][tid][0];
    pp[1] = hp[0][tid][1] + hp[1][tid][1];
    pp[2] = hp[0][tid][2] + hp[1][tid][2];
  }
}

// ---------------------------------------------------------------------------
// score finish: per row, fold the 8 (S1,S2,D) partials;
// P = inv*D - inv*mu*C1 + C2 + kd_b,  C1 = sum kw*g, C2 = sum kw*b.
// ---------------------------------------------------------------------------
__global__ __launch_bounds__(256) void vas_score(
    const float* __restrict__ part, const float* __restrict__ kw,
    const float* __restrict__ g, const float* __restrict__ b,
    const float* __restrict__ kb, float* __restrict__ score, int N) {
  const int tid = threadIdx.x, lane = tid & 63, wave = tid >> 6;
  __shared__ float shc[2][4];
  f32x4 kv = ((const f32x4*)kw)[tid];
  f32x4 gv = ((const f32x4*)g)[tid];
  f32x4 bv = ((const f32x4*)b)[tid];
  float c1 = kv.x * gv.x + kv.y * gv.y + kv.z * gv.z + kv.w * gv.w;
  float c2 = kv.x * bv.x + kv.y * bv.y + kv.z * bv.z + kv.w * bv.w;
#pragma unroll
  for (int off = 32; off; off >>= 1) {
    c1 += __shfl_xor(c1, off);
    c2 += __shfl_xor(c2, off);
  }
  if (lane == 0) { shc[0][wave] = c1; shc[1][wave] = c2; }
  __syncthreads();
  float C1 = shc[0][0] + shc[0][1] + shc[0][2] + shc[0][3];
  float C2 = shc[1][0] + shc[1][1] + shc[1][2] + shc[1][3];
  int row = blockIdx.x * 256 + tid;
  if (row < N) {
    const float* pp = part + (size_t)row * 24;
    float s1 = 0.f, s2 = 0.f, dd = 0.f;
#pragma unroll
    for (int k = 0; k < 8; ++k) {
      s1 += pp[k * 3];
      s2 += pp[k * 3 + 1];
      dd += pp[k * 3 + 2];
    }
    float mu = s1 / 1024.f;
    float var = s2 / 1024.f - mu * mu;
    float inv = rsqrtf(var + 1e-6f);
    float P = inv * dd - inv * mu * C1 + C2 + kb[0];
    score[row] = 1.f / (1.f + __expf(-P));
  }
}

// ---------------------------------------------------------------------------
// Fused banded attention softmax (band computation only — att_comb
// materialization rides on apply_ln/gemmh writer blocks for overlap).
// Q folded into K: logit(i,j) = x_i . KK_j with KK = x @ (Wq^T Wk)^T.
// ---------------------------------------------------------------------------
__global__ __launch_bounds__(256) void vas_battn(
    const u16* __restrict__ Xv, const u16* __restrict__ Xa,
    const u16* __restrict__ KKVv, const u16* __restrict__ KKVa,
    float* __restrict__ bandV, float* __restrict__ bandA,
    int N, float scale, int vb) {
  const int lane = threadIdx.x & 63;
  const int wave = threadIdx.x >> 6;
  const bool video = blockIdx.x < (u32)vb;
  const int i = (video ? blockIdx.x : blockIdx.x - vb) * 4 + wave;
  const int lo = imax(i - 19, 0);
  const int hi = imin(i + 19, N - 1);
  const int nj = hi - lo + 1;
  float logit = 0.f;

  if (video) {
    float qf[16];
    const u16* qrow = Xv + (size_t)i * 1024;
#pragma unroll
    for (int c = 0; c < 2; ++c) {
      bf16x8 qv = *(const bf16x8*)(qrow + c * 512 + lane * 8);
      const u32* qw = (const u32*)&qv;
#pragma unroll
      for (int t = 0; t < 4; ++t) {
        qf[c * 8 + 2 * t] = lo16(qw[t]);
        qf[c * 8 + 2 * t + 1] = hi16(qw[t]);
      }
    }
#pragma unroll 2
    for (int s = 0; s < nj; ++s) {
      const u16* kr = KKVv + (size_t)(lo + s) * 2048;
      float p = 0.f;
#pragma unroll
      for (int c = 0; c < 2; ++c) {
        bf16x8 kv = *(const bf16x8*)(kr + c * 512 + lane * 8);
        const u32* kw = (const u32*)&kv;
#pragma unroll
        for (int t = 0; t < 4; ++t)
          p += lo16(kw[t]) * qf[c * 8 + 2 * t] + hi16(kw[t]) * qf[c * 8 + 2 * t + 1];
      }
#pragma unroll
      for (int off = 32; off; off >>= 1) p += __shfl_xor(p, off);
      if (lane == s) logit = p;
    }
  } else {
    u32 q = *(const u32*)(Xa + (size_t)i * 128 + lane * 2);
    float q0 = lo16(q), q1 = hi16(q);
#pragma unroll 2
    for (int s = 0; s < nj; ++s) {
      u32 k = *(const u32*)(KKVa + (size_t)(lo + s) * 256 + lane * 2);
      float p = lo16(k) * q0 + hi16(k) * q1;
#pragma unroll
      for (int off = 32; off; off >>= 1) p += __shfl_xor(p, off);
      if (lane == s) logit = p;
    }
  }

  logit *= scale;
  float v = (lane < nj) ? logit : -3.4e38f;
  float mx = v;
#pragma unroll
  for (int off = 32; off; off >>= 1) mx = fmaxf(mx, __shfl_xor(mx, off));
  float e = (lane < nj) ? __expf(v - mx) : 0.f;
  float den = e;
#pragma unroll
  for (int off = 32; off; off >>= 1) den += __shfl_xor(den, off);
  float att = (lane < nj) ? e / den : 0.f;
  float* band = video ? bandV : bandA;
  if (lane < 40) band[i * 40 + lane] = att;
}

// ---------------------------------------------------------------------------
// Fused apply + residual + LayerNorm + appended att_comb writer blocks
// (rows [0, wsplit) — the rest ride on vas_gemmh).
//   ycomb[j, 0:1024]   = LN( (att.T @ V')[j] + x[j]  ) * g + b      (video)
//   ycomb[j, 1024:1152]= LN( (attA.T @ Va')[j] + xa[j]) * ga + ba   (audio)
// V' carries Wo folded in. JT=8 (JT=16 halved occupancy, R3).
// ---------------------------------------------------------------------------
#define JT 8
__global__ __launch_bounds__(256) void vas_apply_ln(
    const u16* __restrict__ KKVv, const u16* __restrict__ KKVa,
    const float* __restrict__ bandV, const float* __restrict__ bandA,
    const float* __restrict__ Xv, const float* __restrict__ Xa,
    const float* __restrict__ gv, const float* __restrict__ bv_,
    const float* __restrict__ ga, const float* __restrict__ ba,
    u16* __restrict__ out, int outStride, int N, int vb,
    float* __restrict__ attBase) {
  const int tid = threadIdx.x;
  __shared__ float a_sh[(JT + 38) * JT];
  __shared__ float red[2][JT][4];
  const int ab = vb + (N >> 2);  // audio blocks end; writers follow

  if (blockIdx.x < (u32)vb) {
    const int j0 = blockIdx.x * JT;
    const int base = j0 - 19;
    for (int idx = tid; idx < (JT + 38) * JT; idx += 256) {
      int s = idx / JT, jj = idx % JT;
      int i = base + s;
      int j = j0 + jj;
      float w = 0.f;
      if (i >= 0 && i < N) {
        int d = j - i;
        if (d > -20 && d < 20) w = bandV[i * 40 + (j - imax(i - 19, 0))];
      }
      a_sh[s * JT + jj] = w;
    }
    __syncthreads();

    f32x4 acc[JT] = {};
    const int sLo = imax(0, -base);
    const int sHi = imin(JT + 38, N - base);
    s16x4 nxt = *(const s16x4*)(KKVv + (size_t)(base + sLo) * 2048 + 1024 + tid * 4);
    for (int s = sLo; s < sHi; ++s) {
      s16x4 raw = nxt;
      if (s + 1 < sHi)
        nxt = *(const s16x4*)(KKVv + (size_t)(base + s + 1) * 2048 + 1024 + tid * 4);
      f32x4 vv;
      vv.x = bf2f((u16)raw.x);
      vv.y = bf2f((u16)raw.y);
      vv.z = bf2f((u16)raw.z);
      vv.w = bf2f((u16)raw.w);
#pragma unroll
      for (int jj = 0; jj < JT; ++jj) {
        float a = a_sh[s * JT + jj];
        acc[jj].x += a * vv.x;
        acc[jj].y += a * vv.y;
        acc[jj].z += a * vv.z;
        acc[jj].w += a * vv.w;
      }
    }

    // residual + LN epilogue (each thread owns cols tid*4..tid*4+3 of JT rows)
    const int lane = tid & 63, wave = tid >> 6;
#pragma unroll
    for (int jj = 0; jj < JT; ++jj) {
      f32x4 x4 = ((const f32x4*)(Xv + (size_t)(j0 + jj) * 1024))[tid];
      f32x4 v;
      v.x = acc[jj].x + x4.x;
      v.y = acc[jj].y + x4.y;
      v.z = acc[jj].z + x4.z;
      v.w = acc[jj].w + x4.w;
      acc[jj] = v;
      float s = v.x + v.y + v.z + v.w;
      float s2 = v.x * v.x + v.y * v.y + v.z * v.z + v.w * v.w;
#pragma unroll
      for (int off = 32; off; off >>= 1) {
        s += __shfl_xor(s, off);
        s2 += __shfl_xor(s2, off);
      }
      if (lane == 0) { red[0][jj][wave] = s; red[1][jj][wave] = s2; }
    }
    __syncthreads();
    f32x4 gg = ((const f32x4*)gv)[tid];
    f32x4 bb = ((const f32x4*)bv_)[tid];
#pragma unroll
    for (int jj = 0; jj < JT; ++jj) {
      float S = red[0][jj][0] + red[0][jj][1] + red[0][jj][2] + red[0][jj][3];
      float S2 = red[1][jj][0] + red[1][jj][1] + red[1][jj][2] + red[1][jj][3];
      float mu = S / 1024.f;
      float var = S2 / 1024.f - mu * mu;
      float inv = rsqrtf(var + 1e-6f);
      f32x4 v = acc[jj];
      s16x4 o;
      o.x = (short)f2bf((v.x - mu) * inv * gg.x + bb.x);
      o.y = (short)f2bf((v.y - mu) * inv * gg.y + bb.y);
      o.z = (short)f2bf((v.z - mu) * inv * gg.z + bb.z);
      o.w = (short)f2bf((v.w - mu) * inv * gg.w + bb.w);
      *(s16x4*)(out + (size_t)(j0 + jj) * outStride + tid * 4) = o;
    }
  } else if (blockIdx.x < (u32)ab) {
    const int lane = tid & 63;
    const int wave = tid >> 6;
    const int j = (blockIdx.x - vb) * 4 + wave;
    const int lo = imax(j - 19, 0);
    const int hi = imin(j + 19, N - 1);
    const int ni = hi - lo + 1;
    float* aw = a_sh + wave * 40;
    if (lane < ni) {
      int i = lo + lane;
      aw[lane] = bandA[i * 40 + (j - imax(i - 19, 0))];
    }
    __syncthreads();
    f32x2 acc = {0.f, 0.f};
#pragma unroll 4
    for (int s = 0; s < ni; ++s) {
      float a = aw[s];
      u32 k = *(const u32*)(KKVa + (size_t)(lo + s) * 256 + 128 + lane * 2);
      acc.x += a * lo16(k);
      acc.y += a * hi16(k);
    }
    // residual + wave-level LN over the 128-wide row
    f32x2 x2 = *(const f32x2*)(Xa + (size_t)j * 128 + lane * 2);
    float vx = acc.x + x2.x;
    float vy = acc.y + x2.y;
    float s = vx + vy, s2 = vx * vx + vy * vy;
#pragma unroll
    for (int off = 32; off; off >>= 1) {
      s += __shfl_xor(s, off);
      s2 += __shfl_xor(s2, off);
    }
    float mu = s / 128.f;
    float var = s2 / 128.f - mu * mu;
    float inv = rsqrtf(var + 1e-6f);
    f32x2 g2 = *(const f32x2*)(ga + lane * 2);
    f32x2 b2 = *(const f32x2*)(ba + lane * 2);
    u32 o = (u32)f2bf((vx - mu) * inv * g2.x + b2.x) |
            ((u32)f2bf((vy - mu) * inv * g2.y + b2.y) << 16);
    *(u32*)(out + (size_t)j * outStride + 1024 + lane * 2) = o;
  } else {
    // att_comb writer rows [0, wsplit): reuse a_sh as the 80-float scratch
    write_att_row(blockIdx.x - ab, bandV, bandA, attBase, N, tid, a_sh);
  }
}

// ---------------------------------------------------------------------------
extern "C" void kernel_launch(void* const* d_in, const int* in_sizes, int n_in,
                              void* d_out, int out_size, void* d_ws, size_t ws_size,
                              hipStream_t stream) {
  const float* x = (const float*)d_in[0];
  const float* xa = (const float*)d_in[1];
  const float* Wk_v = (const float*)d_in[4];
  const float* Wq_v = (const float*)d_in[5];
  const float* Wv_v = (const float*)d_in[6];
  const float* Wo_v = (const float*)d_in[7];
  const float* Wk_a = (const float*)d_in[8];
  const float* Wq_a = (const float*)d_in[9];
  const float* Wv_a = (const float*)d_in[10];
  const float* Wo_a = (const float*)d_in[11];
  const float* ka_w = (const float*)d_in[12];
  const float* ka_b = (const float*)d_in[13];
  const float* kd_w = (const float*)d_in[14];
  const float* kd_b = (const float*)d_in[15];
  const float* ln_y_g = (const float*)d_in[16];
  const float* ln_y_b = (const float*)d_in[17];
  const float* ln_ya_g = (const float*)d_in[18];
  const float* ln_ya_b = (const float*)d_in[19];
  const float* ln_ka_g = (const float*)d_in[20];
  const float* ln_ka_b = (const float*)d_in[21];

  const int N = in_sizes[0] / 1024;  // 6144
  const int MV = 1024, MA = 128, MH = 1152;
  const int WSPLIT = N / 2;          // att rows written by apply_ln

  char* wsb = (char*)d_ws;
  size_t off = 0;
  auto alloc = [&](size_t bytes) -> void* {
    void* p = wsb + off;
    off += (bytes + 255) & ~(size_t)255;
    return p;
  };
  u16* xf_b   = (u16*)alloc((size_t)N * MV * 2);
  u16* xa_b   = (u16*)alloc((size_t)N * MA * 2);
  u16* wov_b  = (u16*)alloc((size_t)MV * MV * 2);       // Wo_v bf16
  u16* woa_b  = (u16*)alloc((size_t)MA * MA * 2);
  u16* wqTv   = (u16*)alloc((size_t)MV * MV * 2);       // Wq_v^T bf16
  u16* wkTv   = (u16*)alloc((size_t)MV * MV * 2);
  u16* wvTv   = (u16*)alloc((size_t)MV * MV * 2);
  u16* wqTa   = (u16*)alloc((size_t)MA * MA * 2);
  u16* wkTa   = (u16*)alloc((size_t)MA * MA * 2);
  u16* wvTa   = (u16*)alloc((size_t)MA * MA * 2);
  u16* wWv    = (u16*)alloc((size_t)2 * MV * MV * 2);   // rows: G | U=Wo@Wv
  u16* wWa    = (u16*)alloc((size_t)2 * MA * MA * 2);
  u16* kaw_b  = (u16*)alloc((size_t)1024 * MH * 2);
  u16* KKVv   = (u16*)alloc((size_t)N * 2 * MV * 2);    // bf16, cols KK|V'
  u16* KKVa   = (u16*)alloc((size_t)N * 2 * MA * 2);
  float* bandV = (float*)alloc((size_t)N * 40 * 4);
  float* bandA = (float*)alloc((size_t)N * 40 * 4);
  u16* ycomb_b = (u16*)alloc((size_t)N * MH * 2);
  float* part_b = (float*)alloc((size_t)N * 8 * 3 * 4);  // head partials

  float* dout = (float*)d_out;
  float* attBase = dout + N;

  // 1) merged prep: casts + weight transposes in one launch
  {
    CastTab t;
    int c = 0, cum = 0;
    auto seg = [&](const float* s, u16* d, size_t n) {
      t.src[c] = s; t.dst[c] = d; t.start[c] = cum; cum += (int)(n / 4); ++c;
    };
    seg(x, xf_b, (size_t)N * MV);
    seg(xa, xa_b, (size_t)N * MA);
    seg(Wo_v, wov_b, (size_t)MV * MV);
    seg(Wo_a, woa_b, (size_t)MA * MA);
    seg(ka_w, kaw_b, (size_t)1024 * MH);
    t.start[c] = cum;
    int castBlocks = (cum + 255) / 256;

    TransTab tt;
    int c2 = 0, cum2 = 0;
    auto seg2 = [&](const float* s, u16* d, int n) {
      tt.src[c2] = s; tt.dst[c2] = d; tt.n[c2] = n; tt.start[c2] = cum2;
      cum2 += (n / 32) * (n / 32); ++c2;
    };
    seg2(Wq_v, wqTv, MV);
    seg2(Wk_v, wkTv, MV);
    seg2(Wv_v, wvTv, MV);
    seg2(Wq_a, wqTa, MA);
    seg2(Wk_a, wkTa, MA);
    seg2(Wv_a, wvTa, MA);
    tt.start[c2] = cum2;

    vas_prep<<<castBlocks + cum2, 256, 0, stream>>>(t, cum, castBlocks, tt);
  }

  // 1c) combine GEMMs in one launch:
  //     G = Wq^T @ Wk  (logit(i,j) = x_i G x_j^T  -> KK = x @ G^T)
  //     U = Wo  @ Wv   (y = att^T @ (x @ U^T), output proj folded)
  {
    GemmP gv = {wqTv, wkTv, wWv, nullptr, MV, MV, MV, 2};
    GemmP uv = {wov_b, wvTv, wWv + (size_t)MV * MV, nullptr, MV, MV, MV, 2};
    GemmP ga = {wqTa, wkTa, wWa, nullptr, MA, MA, MA, 2};
    GemmP ua = {woa_b, wvTa, wWa + (size_t)MA * MA, nullptr, MA, MA, MA, 2};
    int bg = (MV / 128) * (MV / 128);  // 64
    vas_gemm4<<<2 * bg + 2, 256, 0, stream>>>(gv, uv, ga, ua, bg, 2 * bg, 2 * bg + 1);
  }

  // 2) fused KK|V' projections (video + audio in one grid), bf16 out
  {
    GemmP pv = {xf_b, wWv, KKVv, nullptr, N, 2 * MV, MV, 2};
    GemmP pa = {xa_b, wWa, KKVa, nullptr, N, 2 * MA, MA, 2};
    int bv = (N / 128) * (2 * MV / 128);
    int ba = (N / 128) * (2 * MA / 128);
    vas_gemm4<<<bv + ba, 256, 0, stream>>>(pv, pa, pa, pa, bv, bv + ba, bv + ba);
  }

  // 3) banded softmax -> bands only
  vas_battn<<<N / 2, 256, 0, stream>>>(xf_b, xa_b, KKVv, KKVa, bandV, bandA,
                                       N, 0.06f, N / 4);

  // 4) fused apply + residual + LN -> ycomb, + att_comb writers [0, WSPLIT)
  vas_apply_ln<<<N / JT + N / 4 + WSPLIT, 256, 0, stream>>>(
      KKVv, KKVa, bandV, bandA, x, xa,
      ln_y_g, ln_y_b, ln_ya_g, ln_ya_b, ycomb_b, MH, N, N / JT, attBase);

  // 5) h-GEMM with fused head partials + att_comb writers [WSPLIT, N)
  {
    GemmP ph = {ycomb_b, kaw_b, nullptr, ka_b, N, 1024, MH, 1};
    int bh = (N / 128) * (1024 / 128);
    vas_gemmh<<<bh + (N - WSPLIT), 256, 0, stream>>>(
        ph, kd_w, ln_ka_g, part_b, bh, bandV, bandA, attBase, N, WSPLIT);
  }

  // 6) score finish
  vas_score<<<(N + 255) / 256, 256, 0, stream>>>(
      part_b, kd_w, ln_ka_g, ln_ka_b, kd_b, dout, N);
}

// Round 8
// 526.322 us; speedup vs baseline: 1.0147x; 1.0147x over previous
//
#include <hip/hip_runtime.h>
#include <stdint.h>

typedef unsigned short u16;
typedef unsigned int u32;
typedef __attribute__((ext_vector_type(8))) short bf16x8;
typedef __attribute__((ext_vector_type(4))) short s16x4;
typedef __attribute__((ext_vector_type(4))) float f32x4;
typedef __attribute__((ext_vector_type(2))) float f32x2;

#define DEV __device__ __forceinline__

DEV u16 f2bf(float f) {
  union { float f; unsigned u; } v; v.f = f;
  unsigned r = v.u + 0x7fffu + ((v.u >> 16) & 1u);
  return (u16)(r >> 16);
}
DEV float bf2f(u16 h) {
  union { u32 u; float f; } v; v.u = ((u32)h) << 16; return v.f;
}
DEV float lo16(u32 w) { union { u32 u; float f; } v; v.u = w << 16; return v.f; }
DEV float hi16(u32 w) { union { u32 u; float f; } v; v.u = w & 0xFFFF0000u; return v.f; }
DEV int imax(int a, int b) { return a > b ? a : b; }
DEV int imin(int a, int b) { return a < b ? a : b; }

// bijective XCD-chunk swizzle (m204 form) — used ONLY within GEMM segments.
DEV int xcd_swz(int b0, int nwg) {
  int q = nwg >> 3, r = nwg & 7, x = b0 & 7, l = b0 >> 3;
  return (x < r ? x * (q + 1) : r * (q + 1) + (x - r) * q) + l;
}

DEV void g2lds16(const u16* g, u16* l) {
  __builtin_amdgcn_global_load_lds(
      (const __attribute__((address_space(1))) void*)g,
      (__attribute__((address_space(3))) void*)l, 16, 0, 0);
}

// att_comb writer: one block streams row i (video + audio halves) with NT
// stores from the L2-hot band buffers. bw = 80-float shared scratch.
// Lives ONLY under the MFMA-bound gemmh (R7 showed pairing writers with the
// BW-hungry apply_ln stretches both).
DEV void write_att_row(int i, const float* __restrict__ bandV,
                       const float* __restrict__ bandA,
                       float* __restrict__ attBase, int N, int tid,
                       float* bw) {
  const int lo = imax(i - 19, 0);
  const int hi = imin(i + 19, N - 1);
  if (tid < 40) bw[tid] = bandV[i * 40 + tid];
  else if (tid < 80) bw[tid] = bandA[i * 40 + (tid - 40)];
  __syncthreads();
  const int nch = N / 4;
  const int cLo = lo >> 2, cHi = hi >> 2;
  f32x4* rowp = (f32x4*)(attBase + (size_t)i * 2 * N);
#pragma unroll 1
  for (int half = 0; half < 2; ++half) {
    const float* w = bw + half * 40;
    f32x4* rp = rowp + half * nch;
    for (int c = tid; c < nch; c += 256) {
      f32x4 o = {0.f, 0.f, 0.f, 0.f};
      if (c >= cLo && c <= cHi) {
        int col0 = c * 4;
#pragma unroll
        for (int e2 = 0; e2 < 4; ++e2) {
          int col = col0 + e2;
          if (col >= lo && col <= hi) o[e2] = w[col - lo];
        }
      }
      __builtin_nontemporal_store(o, &rp[c]);
    }
  }
}

// ---------------------------------------------------------------------------
// multi-segment f32 -> bf16 cast table (shared by prep and combine kernels)
// ---------------------------------------------------------------------------
#define NSEG 5
struct CastTab {
  const float* src[NSEG];
  u16* dst[NSEG];
  int start[NSEG + 1];
};

DEV void cast_block(const CastTab& t, int idx, int total4) {
  if (idx >= total4) return;
  int s = 0;
#pragma unroll
  for (int k = 1; k < NSEG; ++k)
    if (idx >= t.start[k]) s = k;
  int local = idx - t.start[s];
  f32x4 f = ((const f32x4*)t.src[s])[local];
  s16x4 o;
  o.x = (short)f2bf(f.x);
  o.y = (short)f2bf(f.y);
  o.z = (short)f2bf(f.z);
  o.w = (short)f2bf(f.w);
  ((s16x4*)t.dst[s])[local] = o;
}

// ---------------------------------------------------------------------------
// prep: combine-GEMM prerequisites only — 6 weight transposes (f32->bf16^T)
// + Wo_v/Wo_a casts. The big x/xa/ka_w casts ride on vas_combine instead.
// ---------------------------------------------------------------------------
struct TransTab {
  const float* src[6];
  u16* dst[6];
  int n[6];
  int start[7];
};

__global__ __launch_bounds__(256) void vas_prep(CastTab t, int total4,
                                                int castBlocks, TransTab tt) {
  if ((int)blockIdx.x < castBlocks) {
    cast_block(t, blockIdx.x * 256 + threadIdx.x, total4);
  } else {
    __shared__ float tl[32][33];
    int b = blockIdx.x - castBlocks;
    int s = 0;
#pragma unroll
    for (int k = 1; k < 6; ++k)
      if (b >= tt.start[k]) s = k;
    b -= tt.start[s];
    const float* src = tt.src[s];
    u16* dst = tt.dst[s];
    const int n = tt.n[s];
    const int tpr = n >> 5;
    const int tr = (b / tpr) * 32, tc = (b % tpr) * 32;
    const int lx = threadIdx.x & 31, ly = threadIdx.x >> 5;
#pragma unroll
    for (int r = 0; r < 4; ++r)
      tl[ly + r * 8][lx] = src[(size_t)(tr + ly + r * 8) * n + tc + lx];
    __syncthreads();
#pragma unroll
    for (int r = 0; r < 4; ++r)
      dst[(size_t)(tc + ly + r * 8) * n + tr + lx] = f2bf(tl[lx][ly + r * 8]);
  }
}

// ---------------------------------------------------------------------------
// GEMM parameter block. mode 0: f32 out; 1: bf16 relu+bias; 2: bf16 plain.
// ---------------------------------------------------------------------------
struct GemmP {
  const u16* A;
  const u16* W;
  void* C;
  const float* bias;
  int M, Nn, K, mode;
};

// shared 128x128-tile GEMM body (m97 layout, BK=64, 2 barriers per 64 K)
DEV void gemm_body(const GemmP& p, int bid, int tid,
                   u16 (*As)[128 * 32], u16 (*Ws)[128 * 32],
                   f32x4 (*acc)[4]) {
  const int lane = tid & 63;
  const int wave = tid >> 6;

  const int Mb = p.M >> 7, Nb = p.Nn >> 7;
  const int GM = 8;
  int per = GM * Nb;
  int g = bid / per;
  int rem = bid - g * per;
  int gm = imin(GM, Mb - g * GM);
  int mblk = g * GM + rem % gm;
  int nblk = rem / gm;
  const int m0 = mblk * 128;
  const int n0 = nblk * 128;
  const int wm = (wave >> 1) * 64;
  const int wn = (wave & 1) * 64;

  // wave-uniform staging decode: waves 0,1 stage A (khalf 0,1), waves 2,3 W.
  const int smat = wave >> 1;
  const int skh = wave & 1;
  const u16* ssrc = smat ? p.W : p.A;
  const int sbase = smat ? n0 : m0;
  u16* sdstBase = (smat ? &Ws[skh][0] : &As[skh][0]) + lane * 8;
  const int srow = lane >> 2;
  const int scol = (lane & 3) * 8;

  for (int k0 = 0; k0 < p.K; k0 += 64) {
#pragma unroll
    for (int u = 0; u < 8; ++u) {
      int r0 = u * 16;
      g2lds16(ssrc + (size_t)(sbase + r0 + srow) * p.K + (k0 + skh * 32 + scol),
              sdstBase + r0 * 32);
    }
    __syncthreads();
#pragma unroll
    for (int kk = 0; kk < 2; ++kk) {
      bf16x8 af[4], bfr[4];
#pragma unroll
      for (int t = 0; t < 4; ++t)
        af[t] = *(const bf16x8*)(&As[kk][0] + (wm + t * 16 + (lane & 15)) * 32 + (lane >> 4) * 8);
#pragma unroll
      for (int t = 0; t < 4; ++t)
        bfr[t] = *(const bf16x8*)(&Ws[kk][0] + (wn + t * 16 + (lane & 15)) * 32 + (lane >> 4) * 8);
#pragma unroll
      for (int mi = 0; mi < 4; ++mi)
#pragma unroll
        for (int ni = 0; ni < 4; ++ni)
          acc[mi][ni] = __builtin_amdgcn_mfma_f32_16x16x32_bf16(af[mi], bfr[ni], acc[mi][ni], 0, 0, 0);
    }
    __syncthreads();
  }
}

DEV void gemm_store(const GemmP& p, int bid, int tid, f32x4 (*acc)[4]) {
  const int lane = tid & 63;
  const int wave = tid >> 6;
  const int Mb = p.M >> 7, Nb = p.Nn >> 7;
  const int GM = 8;
  int per = GM * Nb;
  int g = bid / per;
  int rem = bid - g * per;
  int gm = imin(GM, Mb - g * GM);
  int mblk = g * GM + rem % gm;
  int nblk = rem / gm;
  const int m0 = mblk * 128;
  const int n0 = nblk * 128;
  const int wm = (wave >> 1) * 64;
  const int wn = (wave & 1) * 64;
#pragma unroll
  for (int mi = 0; mi < 4; ++mi) {
#pragma unroll
    for (int ni = 0; ni < 4; ++ni) {
      int col = n0 + wn + ni * 16 + (lane & 15);
      float bv = p.bias ? p.bias[col] : 0.f;
#pragma unroll
      for (int r = 0; r < 4; ++r) {
        int row = m0 + wm + mi * 16 + (lane >> 4) * 4 + r;
        float vv = acc[mi][ni][r] + bv;
        size_t idx = (size_t)row * p.Nn + col;
        if (p.mode == 0) ((float*)p.C)[idx] = vv;
        else if (p.mode == 1) ((u16*)p.C)[idx] = f2bf(fmaxf(vv, 0.f));
        else ((u16*)p.C)[idx] = f2bf(vv);
      }
    }
  }
}

// ---------------------------------------------------------------------------
// 4-way segmented bf16 GEMM (KKV projections etc.)
// ---------------------------------------------------------------------------
__global__ __launch_bounds__(256) void vas_gemm4(
    GemmP p0, GemmP p1, GemmP p2, GemmP p3, int s1, int s2, int s3) {
  const int bs = xcd_swz(blockIdx.x, gridDim.x);
  GemmP p;
  int bid;
  if (bs < s1) { p = p0; bid = bs; }
  else if (bs < s2) { p = p1; bid = bs - s1; }
  else if (bs < s3) { p = p2; bid = bs - s2; }
  else { p = p3; bid = bs - s3; }

  __shared__ u16 As[2][128 * 32];
  __shared__ u16 Ws[2][128 * 32];
  f32x4 acc[4][4] = {};
  gemm_body(p, bid, threadIdx.x, As, Ws, acc);
  gemm_store(p, bid, threadIdx.x, acc);
}

// ---------------------------------------------------------------------------
// combine launch: blocks [0, gb) run the 4 weight-combine GEMMs
// (G = Wq^T Wk, U = Wo Wv, video + audio); blocks [gb, ...) cast x/xa/ka_w.
// The small GEMM grid (~130 blocks) leaves most CUs idle — the BW-bound cast
// backfills them (same heterogeneous-grid pattern as gemmh's writers).
// ---------------------------------------------------------------------------
__global__ __launch_bounds__(256) void vas_combine(
    GemmP p0, GemmP p1, GemmP p2, GemmP p3, int s1, int s2, int s3,
    int gb, CastTab ct, int total4) {
  if ((int)blockIdx.x >= gb) {
    cast_block(ct, (blockIdx.x - gb) * 256 + threadIdx.x, total4);
    return;
  }
  const int bs = xcd_swz(blockIdx.x, gb);
  GemmP p;
  int bid;
  if (bs < s1) { p = p0; bid = bs; }
  else if (bs < s2) { p = p1; bid = bs - s1; }
  else if (bs < s3) { p = p2; bid = bs - s2; }
  else { p = p3; bid = bs - s3; }

  __shared__ u16 As[2][128 * 32];
  __shared__ u16 Ws[2][128 * 32];
  f32x4 acc[4][4] = {};
  gemm_body(p, bid, threadIdx.x, As, Ws, acc);
  gemm_store(p, bid, threadIdx.x, acc);
}

// ---------------------------------------------------------------------------
// h-GEMM with fused head partials + ALL att_comb writer blocks (R6 schedule:
// the streaming write overlaps the MFMA-bound GEMM on other CUs).
// ---------------------------------------------------------------------------
__global__ __launch_bounds__(256) void vas_gemmh(
    GemmP p, const float* __restrict__ kw, const float* __restrict__ gw,
    float* __restrict__ part, int bh,
    const float* __restrict__ bandV, const float* __restrict__ bandA,
    float* __restrict__ attBase, int N) {
  const int tid = threadIdx.x;

  if ((int)blockIdx.x >= bh) {
    __shared__ float bw[80];
    write_att_row(blockIdx.x - bh, bandV, bandA, attBase, N, tid, bw);
    return;
  }

  const int bid = xcd_swz(blockIdx.x, bh);

  __shared__ u16 As[2][128 * 32];
  __shared__ u16 Ws[2][128 * 32];
  __shared__ float hp[2][128][3];
  const int lane = tid & 63;
  const int wave = tid >> 6;

  f32x4 acc[4][4] = {};
  gemm_body(p, bid, tid, As, Ws, acc);

  // recompute tile coords (as gemm_store does)
  const int Mb = p.M >> 7, Nb = p.Nn >> 7;
  const int GM = 8;
  int per = GM * Nb;
  int g = bid / per;
  int rem = bid - g * per;
  int gm = imin(GM, Mb - g * GM);
  int mblk = g * GM + rem % gm;
  int nblk = rem / gm;
  const int m0 = mblk * 128;
  const int n0 = nblk * 128;
  const int wm = (wave >> 1) * 64;
  const int wn = (wave & 1) * 64;

  // per-row head partials: 16-lane shfl tree over cols, LDS pair-sum of the
  // two waves covering the same 64 rows.
  float kwg[4], bb[4];
#pragma unroll
  for (int ni = 0; ni < 4; ++ni) {
    int col = n0 + wn + ni * 16 + (lane & 15);
    kwg[ni] = kw[col] * gw[col];
    bb[ni] = p.bias ? p.bias[col] : 0.f;
  }
#pragma unroll
  for (int mi = 0; mi < 4; ++mi) {
#pragma unroll
    for (int r = 0; r < 4; ++r) {
      float s1 = 0.f, s2 = 0.f, dd = 0.f;
#pragma unroll
      for (int ni = 0; ni < 4; ++ni) {
        float vv = fmaxf(acc[mi][ni][r] + bb[ni], 0.f);
        s1 += vv;
        s2 += vv * vv;
        dd += vv * kwg[ni];
      }
#pragma unroll
      for (int off = 1; off < 16; off <<= 1) {
        s1 += __shfl_xor(s1, off);
        s2 += __shfl_xor(s2, off);
        dd += __shfl_xor(dd, off);
      }
      if ((lane & 15) == 0) {
        int row = wm + mi * 16 + (lane >> 4) * 4 + r;
        hp[wave & 1][row][0] = s1;
        hp[wave & 1][row][1] = s2;
        hp[wave & 1][row][2] = dd;
      }
    }
  }
  __syncthreads();
  if (tid < 128) {
    float* pp = part + ((size_t)(m0 + tid) * 8 + nblk) * 3;
    pp[0] = hp[0][tid][0] + hp[1][tid][0];
    pp[1] = hp[0][tid][1] + hp[1][tid][1];
    pp[2] = hp[0][tid][2] + hp[1][tid][2];
  }
}

// ---------------------------------------------------------------------------
// score finish: per row, fold the 8 (S1,S2,D) partials;
// P = inv*D - inv*mu*C1 + C2 + kd_b,  C1 = sum kw*g, C2 = sum kw*b.
// ---------------------------------------------------------------------------
__global__ __launch_bounds__(256) void vas_score(
    const float* __restrict__ part, const float* __restrict__ kw,
    const float* __restrict__ g, const float* __restrict__ b,
    const float* __restrict__ kb, float* __restrict__ score, int N) {
  const int tid = threadIdx.x, lane = tid & 63, wave = tid >> 6;
  __shared__ float shc[2][4];
  f32x4 kv = ((const f32x4*)kw)[tid];
  f32x4 gv = ((const f32x4*)g)[tid];
  f32x4 bv = ((const f32x4*)b)[tid];
  float c1 = kv.x * gv.x + kv.y * gv.y + kv.z * gv.z + kv.w * gv.w;
  float c2 = kv.x * bv.x + kv.y * bv.y + kv.z * bv.z + kv.w * bv.w;
#pragma unroll
  for (int off = 32; off; off >>= 1) {
    c1 += __shfl_xor(c1, off);
    c2 += __shfl_xor(c2, off);
  }
  if (lane == 0) { shc[0][wave] = c1; shc[1][wave] = c2; }
  __syncthreads();
  float C1 = shc[0][0] + shc[0][1] + shc[0][2] + shc[0][3];
  float C2 = shc[1][0] + shc[1][1] + shc[1][2] + shc[1][3];
  int row = blockIdx.x * 256 + tid;
  if (row < N) {
    const float* pp = part + (size_t)row * 24;
    float s1 = 0.f, s2 = 0.f, dd = 0.f;
#pragma unroll
    for (int k = 0; k < 8; ++k) {
      s1 += pp[k * 3];
      s2 += pp[k * 3 + 1];
      dd += pp[k * 3 + 2];
    }
    float mu = s1 / 1024.f;
    float var = s2 / 1024.f - mu * mu;
    float inv = rsqrtf(var + 1e-6f);
    float P = inv * dd - inv * mu * C1 + C2 + kb[0];
    score[row] = 1.f / (1.f + __expf(-P));
  }
}

// ---------------------------------------------------------------------------
// Fused banded attention softmax (band computation only).
// Q folded into K: logit(i,j) = x_i . KK_j with KK = x @ (Wq^T Wk)^T.
// ---------------------------------------------------------------------------
__global__ __launch_bounds__(256) void vas_battn(
    const u16* __restrict__ Xv, const u16* __restrict__ Xa,
    const u16* __restrict__ KKVv, const u16* __restrict__ KKVa,
    float* __restrict__ bandV, float* __restrict__ bandA,
    int N, float scale, int vb) {
  const int lane = threadIdx.x & 63;
  const int wave = threadIdx.x >> 6;
  const bool video = blockIdx.x < (u32)vb;
  const int i = (video ? blockIdx.x : blockIdx.x - vb) * 4 + wave;
  const int lo = imax(i - 19, 0);
  const int hi = imin(i + 19, N - 1);
  const int nj = hi - lo + 1;
  float logit = 0.f;

  if (video) {
    float qf[16];
    const u16* qrow = Xv + (size_t)i * 1024;
#pragma unroll
    for (int c = 0; c < 2; ++c) {
      bf16x8 qv = *(const bf16x8*)(qrow + c * 512 + lane * 8);
      const u32* qw = (const u32*)&qv;
#pragma unroll
      for (int t = 0; t < 4; ++t) {
        qf[c * 8 + 2 * t] = lo16(qw[t]);
        qf[c * 8 + 2 * t + 1] = hi16(qw[t]);
      }
    }
#pragma unroll 2
    for (int s = 0; s < nj; ++s) {
      const u16* kr = KKVv + (size_t)(lo + s) * 2048;
      float p = 0.f;
#pragma unroll
      for (int c = 0; c < 2; ++c) {
        bf16x8 kv = *(const bf16x8*)(kr + c * 512 + lane * 8);
        const u32* kw = (const u32*)&kv;
#pragma unroll
        for (int t = 0; t < 4; ++t)
          p += lo16(kw[t]) * qf[c * 8 + 2 * t] + hi16(kw[t]) * qf[c * 8 + 2 * t + 1];
      }
#pragma unroll
      for (int off = 32; off; off >>= 1) p += __shfl_xor(p, off);
      if (lane == s) logit = p;
    }
  } else {
    u32 q = *(const u32*)(Xa + (size_t)i * 128 + lane * 2);
    float q0 = lo16(q), q1 = hi16(q);
#pragma unroll 2
    for (int s = 0; s < nj; ++s) {
      u32 k = *(const u32*)(KKVa + (size_t)(lo + s) * 256 + lane * 2);
      float p = lo16(k) * q0 + hi16(k) * q1;
#pragma unroll
      for (int off = 32; off; off >>= 1) p += __shfl_xor(p, off);
      if (lane == s) logit = p;
    }
  }

  logit *= scale;
  float v = (lane < nj) ? logit : -3.4e38f;
  float mx = v;
#pragma unroll
  for (int off = 32; off; off >>= 1) mx = fmaxf(mx, __shfl_xor(mx, off));
  float e = (lane < nj) ? __expf(v - mx) : 0.f;
  float den = e;
#pragma unroll
  for (int off = 32; off; off >>= 1) den += __shfl_xor(den, off);
  float att = (lane < nj) ? e / den : 0.f;
  float* band = video ? bandV : bandA;
  if (lane < 40) band[i * 40 + lane] = att;
}

// ---------------------------------------------------------------------------
// Fused apply + residual + LayerNorm (R6 form — no writer blocks):
//   ycomb[j, 0:1024]   = LN( (att.T @ V')[j] + x[j]  ) * g + b      (video)
//   ycomb[j, 1024:1152]= LN( (attA.T @ Va')[j] + xa[j]) * ga + ba   (audio)
// V' carries Wo folded in. JT=8 (JT=16 halved occupancy, R3).
// ---------------------------------------------------------------------------
#define JT 8
__global__ __launch_bounds__(256) void vas_apply_ln(
    const u16* __restrict__ KKVv, const u16* __restrict__ KKVa,
    const float* __restrict__ bandV, const float* __restrict__ bandA,
    const float* __restrict__ Xv, const float* __restrict__ Xa,
    const float* __restrict__ gv, const float* __restrict__ bv_,
    const float* __restrict__ ga, const float* __restrict__ ba,
    u16* __restrict__ out, int outStride, int N, int vb) {
  const int tid = threadIdx.x;
  __shared__ float a_sh[(JT + 38) * JT];
  __shared__ float red[2][JT][4];

  if (blockIdx.x < (u32)vb) {
    const int j0 = blockIdx.x * JT;
    const int base = j0 - 19;
    for (int idx = tid; idx < (JT + 38) * JT; idx += 256) {
      int s = idx / JT, jj = idx % JT;
      int i = base + s;
      int j = j0 + jj;
      float w = 0.f;
      if (i >= 0 && i < N) {
        int d = j - i;
        if (d > -20 && d < 20) w = bandV[i * 40 + (j - imax(i - 19, 0))];
      }
      a_sh[s * JT + jj] = w;
    }
    __syncthreads();

    f32x4 acc[JT] = {};
    const int sLo = imax(0, -base);
    const int sHi = imin(JT + 38, N - base);
    s16x4 nxt = *(const s16x4*)(KKVv + (size_t)(base + sLo) * 2048 + 1024 + tid * 4);
    for (int s = sLo; s < sHi; ++s) {
      s16x4 raw = nxt;
      if (s + 1 < sHi)
        nxt = *(const s16x4*)(KKVv + (size_t)(base + s + 1) * 2048 + 1024 + tid * 4);
      f32x4 vv;
      vv.x = bf2f((u16)raw.x);
      vv.y = bf2f((u16)raw.y);
      vv.z = bf2f((u16)raw.z);
      vv.w = bf2f((u16)raw.w);
#pragma unroll
      for (int jj = 0; jj < JT; ++jj) {
        float a = a_sh[s * JT + jj];
        acc[jj].x += a * vv.x;
        acc[jj].y += a * vv.y;
        acc[jj].z += a * vv.z;
        acc[jj].w += a * vv.w;
      }
    }

    // residual + LN epilogue (each thread owns cols tid*4..tid*4+3 of JT rows)
    const int lane = tid & 63, wave = tid >> 6;
#pragma unroll
    for (int jj = 0; jj < JT; ++jj) {
      f32x4 x4 = ((const f32x4*)(Xv + (size_t)(j0 + jj) * 1024))[tid];
      f32x4 v;
      v.x = acc[jj].x + x4.x;
      v.y = acc[jj].y + x4.y;
      v.z = acc[jj].z + x4.z;
      v.w = acc[jj].w + x4.w;
      acc[jj] = v;
      float s = v.x + v.y + v.z + v.w;
      float s2 = v.x * v.x + v.y * v.y + v.z * v.z + v.w * v.w;
#pragma unroll
      for (int off = 32; off; off >>= 1) {
        s += __shfl_xor(s, off);
        s2 += __shfl_xor(s2, off);
      }
      if (lane == 0) { red[0][jj][wave] = s; red[1][jj][wave] = s2; }
    }
    __syncthreads();
    f32x4 gg = ((const f32x4*)gv)[tid];
    f32x4 bb = ((const f32x4*)bv_)[tid];
#pragma unroll
    for (int jj = 0; jj < JT; ++jj) {
      float S = red[0][jj][0] + red[0][jj][1] + red[0][jj][2] + red[0][jj][3];
      float S2 = red[1][jj][0] + red[1][jj][1] + red[1][jj][2] + red[1][jj][3];
      float mu = S / 1024.f;
      float var = S2 / 1024.f - mu * mu;
      float inv = rsqrtf(var + 1e-6f);
      f32x4 v = acc[jj];
      s16x4 o;
      o.x = (short)f2bf((v.x - mu) * inv * gg.x + bb.x);
      o.y = (short)f2bf((v.y - mu) * inv * gg.y + bb.y);
      o.z = (short)f2bf((v.z - mu) * inv * gg.z + bb.z);
      o.w = (short)f2bf((v.w - mu) * inv * gg.w + bb.w);
      *(s16x4*)(out + (size_t)(j0 + jj) * outStride + tid * 4) = o;
    }
  } else {
    const int lane = tid & 63;
    const int wave = tid >> 6;
    const int j = (blockIdx.x - vb) * 4 + wave;
    const int lo = imax(j - 19, 0);
    const int hi = imin(j + 19, N - 1);
    const int ni = hi - lo + 1;
    float* aw = a_sh + wave * 40;
    if (lane < ni) {
      int i = lo + lane;
      aw[lane] = bandA[i * 40 + (j - imax(i - 19, 0))];
    }
    __syncthreads();
    f32x2 acc = {0.f, 0.f};
#pragma unroll 4
    for (int s = 0; s < ni; ++s) {
      float a = aw[s];
      u32 k = *(const u32*)(KKVa + (size_t)(lo + s) * 256 + 128 + lane * 2);
      acc.x += a * lo16(k);
      acc.y += a * hi16(k);
    }
    // residual + wave-level LN over the 128-wide row
    f32x2 x2 = *(const f32x2*)(Xa + (size_t)j * 128 + lane * 2);
    float vx = acc.x + x2.x;
    float vy = acc.y + x2.y;
    float s = vx + vy, s2 = vx * vx + vy * vy;
#pragma unroll
    for (int off = 32; off; off >>= 1) {
      s += __shfl_xor(s, off);
      s2 += __shfl_xor(s2, off);
    }
    float mu = s / 128.f;
    float var = s2 / 128.f - mu * mu;
    float inv = rsqrtf(var + 1e-6f);
    f32x2 g2 = *(const f32x2*)(ga + lane * 2);
    f32x2 b2 = *(const f32x2*)(ba + lane * 2);
    u32 o = (u32)f2bf((vx - mu) * inv * g2.x + b2.x) |
            ((u32)f2bf((vy - mu) * inv * g2.y + b2.y) << 16);
    *(u32*)(out + (size_t)j * outStride + 1024 + lane * 2) = o;
  }
}

// ---------------------------------------------------------------------------
extern "C" void kernel_launch(void* const* d_in, const int* in_sizes, int n_in,
                              void* d_out, int out_size, void* d_ws, size_t ws_size,
                              hipStream_t stream) {
  const float* x = (const float*)d_in[0];
  const float* xa = (const float*)d_in[1];
  const float* Wk_v = (const float*)d_in[4];
  const float* Wq_v = (const float*)d_in[5];
  const float* Wv_v = (const float*)d_in[6];
  const float* Wo_v = (const float*)d_in[7];
  const float* Wk_a = (const float*)d_in[8];
  const float* Wq_a = (const float*)d_in[9];
  const float* Wv_a = (const float*)d_in[10];
  const float* Wo_a = (const float*)d_in[11];
  const float* ka_w = (const float*)d_in[12];
  const float* ka_b = (const float*)d_in[13];
  const float* kd_w = (const float*)d_in[14];
  const float* kd_b = (const float*)d_in[15];
  const float* ln_y_g = (const float*)d_in[16];
  const float* ln_y_b = (const float*)d_in[17];
  const float* ln_ya_g = (const float*)d_in[18];
  const float* ln_ya_b = (const float*)d_in[19];
  const float* ln_ka_g = (const float*)d_in[20];
  const float* ln_ka_b = (const float*)d_in[21];

  const int N = in_sizes[0] / 1024;  // 6144
  const int MV = 1024, MA = 128, MH = 1152;

  char* wsb = (char*)d_ws;
  size_t off = 0;
  auto alloc = [&](size_t bytes) -> void* {
    void* p = wsb + off;
    off += (bytes + 255) & ~(size_t)255;
    return p;
  };
  u16* xf_b   = (u16*)alloc((size_t)N * MV * 2);
  u16* xa_b   = (u16*)alloc((size_t)N * MA * 2);
  u16* wov_b  = (u16*)alloc((size_t)MV * MV * 2);       // Wo_v bf16
  u16* woa_b  = (u16*)alloc((size_t)MA * MA * 2);
  u16* wqTv   = (u16*)alloc((size_t)MV * MV * 2);       // Wq_v^T bf16
  u16* wkTv   = (u16*)alloc((size_t)MV * MV * 2);
  u16* wvTv   = (u16*)alloc((size_t)MV * MV * 2);
  u16* wqTa   = (u16*)alloc((size_t)MA * MA * 2);
  u16* wkTa   = (u16*)alloc((size_t)MA * MA * 2);
  u16* wvTa   = (u16*)alloc((size_t)MA * MA * 2);
  u16* wWv    = (u16*)alloc((size_t)2 * MV * MV * 2);   // rows: G | U=Wo@Wv
  u16* wWa    = (u16*)alloc((size_t)2 * MA * MA * 2);
  u16* kaw_b  = (u16*)alloc((size_t)1024 * MH * 2);
  u16* KKVv   = (u16*)alloc((size_t)N * 2 * MV * 2);    // bf16, cols KK|V'
  u16* KKVa   = (u16*)alloc((size_t)N * 2 * MA * 2);
  float* bandV = (float*)alloc((size_t)N * 40 * 4);
  float* bandA = (float*)alloc((size_t)N * 40 * 4);
  u16* ycomb_b = (u16*)alloc((size_t)N * MH * 2);
  float* part_b = (float*)alloc((size_t)N * 8 * 3 * 4);  // head partials

  float* dout = (float*)d_out;
  float* attBase = dout + N;

  // 1) prep: weight transposes + Wo casts (combine-GEMM prerequisites only)
  {
    CastTab t;
    for (int k = 0; k < NSEG; ++k) { t.src[k] = nullptr; t.dst[k] = nullptr; }
    int c = 0, cum = 0;
    auto seg = [&](const float* s, u16* d, size_t n) {
      t.src[c] = s; t.dst[c] = d; t.start[c] = cum; cum += (int)(n / 4); ++c;
    };
    seg(Wo_v, wov_b, (size_t)MV * MV);
    seg(Wo_a, woa_b, (size_t)MA * MA);
    for (int k = c; k <= NSEG; ++k) t.start[k] = cum;
    int castBlocks = (cum + 255) / 256;

    TransTab tt;
    int c2 = 0, cum2 = 0;
    auto seg2 = [&](const float* s, u16* d, int n) {
      tt.src[c2] = s; tt.dst[c2] = d; tt.n[c2] = n; tt.start[c2] = cum2;
      cum2 += (n / 32) * (n / 32); ++c2;
    };
    seg2(Wq_v, wqTv, MV);
    seg2(Wk_v, wkTv, MV);
    seg2(Wv_v, wvTv, MV);
    seg2(Wq_a, wqTa, MA);
    seg2(Wk_a, wkTa, MA);
    seg2(Wv_a, wvTa, MA);
    tt.start[c2] = cum2;

    vas_prep<<<castBlocks + cum2, 256, 0, stream>>>(t, cum, castBlocks, tt);
  }

  // 2) combine GEMMs + overlapped x/xa/ka_w casts in one launch:
  //    G = Wq^T @ Wk, U = Wo @ Wv (video + audio) on ~130 blocks; the
  //    BW-bound casts backfill the idle CUs.
  {
    GemmP gv = {wqTv, wkTv, wWv, nullptr, MV, MV, MV, 2};
    GemmP uv = {wov_b, wvTv, wWv + (size_t)MV * MV, nullptr, MV, MV, MV, 2};
    GemmP ga = {wqTa, wkTa, wWa, nullptr, MA, MA, MA, 2};
    GemmP ua = {woa_b, wvTa, wWa + (size_t)MA * MA, nullptr, MA, MA, MA, 2};
    int bg = (MV / 128) * (MV / 128);  // 64
    int gb = 2 * bg + 2;               // 130 GEMM blocks

    CastTab ct;
    for (int k = 0; k < NSEG; ++k) { ct.src[k] = nullptr; ct.dst[k] = nullptr; }
    int c = 0, cum = 0;
    auto seg = [&](const float* s, u16* d, size_t n) {
      ct.src[c] = s; ct.dst[c] = d; ct.start[c] = cum; cum += (int)(n / 4); ++c;
    };
    seg(x, xf_b, (size_t)N * MV);
    seg(xa, xa_b, (size_t)N * MA);
    seg(ka_w, kaw_b, (size_t)1024 * MH);
    for (int k = c; k <= NSEG; ++k) ct.start[k] = cum;
    int castBlocks = (cum + 255) / 256;

    vas_combine<<<gb + castBlocks, 256, 0, stream>>>(
        gv, uv, ga, ua, bg, 2 * bg, 2 * bg + 1, gb, ct, cum);
  }

  // 3) fused KK|V' projections (video + audio in one grid), bf16 out
  {
    GemmP pv = {xf_b, wWv, KKVv, nullptr, N, 2 * MV, MV, 2};
    GemmP pa = {xa_b, wWa, KKVa, nullptr, N, 2 * MA, MA, 2};
    int bv = (N / 128) * (2 * MV / 128);
    int ba = (N / 128) * (2 * MA / 128);
    vas_gemm4<<<bv + ba, 256, 0, stream>>>(pv, pa, pa, pa, bv, bv + ba, bv + ba);
  }

  // 4) banded softmax -> bands only
  vas_battn<<<N / 2, 256, 0, stream>>>(xf_b, xa_b, KKVv, KKVa, bandV, bandA,
                                       N, 0.06f, N / 4);

  // 5) fused apply + residual + LN -> ycomb
  vas_apply_ln<<<N / JT + N / 4, 256, 0, stream>>>(
      KKVv, KKVa, bandV, bandA, x, xa,
      ln_y_g, ln_y_b, ln_ya_g, ln_ya_b, ycomb_b, MH, N, N / JT);

  // 6) h-GEMM with fused head partials + all att_comb writer blocks
  {
    GemmP ph = {ycomb_b, kaw_b, nullptr, ka_b, N, 1024, MH, 1};
    int bh = (N / 128) * (1024 / 128);
    vas_gemmh<<<bh + N, 256, 0, stream>>>(ph, kd_w, ln_ka_g, part_b, bh,
                                          bandV, bandA, attBase, N);
  }

  // 7) score finish
  vas_score<<<(N + 255) / 256, 256, 0, stream>>>(
      part_b, kd_w, ln_ka_g, ln_ka_b, kd_b, dout, N);
}